// Round 1
// baseline (308.403 us; speedup 1.0000x reference)
//
#include <hip/hip_runtime.h>

// state[e, g, t, c] = (p + p*p) * disp[e, t] * (g+1)   for c in 0..5
// out layout: [n_elem=2048][n_gauss=8][n_time=4096][6]  float32
// Each block handles one (e, g, quarter-of-t-row): 1024 t values = 6144 floats
// = 1536 float4 of contiguous output. 256 threads x 6 float4 stores, coalesced.

#define N_TIME 4096

__global__ __launch_bounds__(256) void state_hist_kernel(
    const float* __restrict__ disp,   // [2048][4096]
    const float* __restrict__ param,  // [1]
    float* __restrict__ out)          // [2048][8][4096][6]
{
    __shared__ float s_disp[1025];

    const int b = blockIdx.x;
    const int j = threadIdx.x;
    const int e     = b >> 5;         // 32 blocks per element (8 gauss * 4 chunks)
    const int g     = (b >> 2) & 7;
    const int tbase = (b & 3) * 1024;

    // Stage this block's 1024 disp values into LDS (float4 coalesced loads).
    const float4* disp4 = reinterpret_cast<const float4*>(disp + e * N_TIME + tbase);
    reinterpret_cast<float4*>(s_disp)[j] = disp4[j];
    if (j == 0) s_disp[1024] = 0.0f;   // pad for unconditional t+1 read
    __syncthreads();

    const float p = param[0];
    const float factor = (p + p * p) * (float)(g + 1);

    float4* out4 = reinterpret_cast<float4*>(out) + (size_t)b * 1536;

    #pragma unroll
    for (int k = 0; k < 6; ++k) {
        const int i4 = k * 256 + j;       // float4 index within block region
        const int r  = i4 * 4;            // float index within block region
        const int t  = r / 6;             // compile-time-const divisor -> mul+shift
        const int c  = r - t * 6;         // in {0, 2, 4}
        const float v0 = factor * s_disp[t];
        const float v1 = factor * s_disp[t + 1];
        float4 o;
        o.x = v0;
        o.y = v0;
        o.z = (c == 4) ? v1 : v0;         // c==4: last two floats belong to t+1
        o.w = (c == 4) ? v1 : v0;
        out4[i4] = o;
    }
}

extern "C" void kernel_launch(void* const* d_in, const int* in_sizes, int n_in,
                              void* d_out, int out_size, void* d_ws, size_t ws_size,
                              hipStream_t stream) {
    const float* disp  = (const float*)d_in[0];   // elements_disp_hist [2048*4096]
    // d_in[1] = time_hist (unused)
    const float* param = (const float*)d_in[2];   // param_1 [1]
    float* out = (float*)d_out;                   // 2048*8*4096*6 floats

    const int n_elem = in_sizes[0] / N_TIME;      // 2048
    const int grid   = n_elem * 8 * 4;            // 65536 blocks

    state_hist_kernel<<<grid, 256, 0, stream>>>(disp, param, out);
}

// Round 3
// 276.676 us; speedup vs baseline: 1.1147x; 1.1147x over previous
//
#include <hip/hip_runtime.h>

// state[e, g, t, c] = (p + p*p) * disp[e, t] * (g+1)   for c in 0..5
// out layout: [n_elem=2048][n_gauss=8][n_time=4096][6]  float32
//
// Work unit: one (e, g, quarter-row) = 1024 t = 6144 floats = 1536 float4
// of contiguous output. 256 threads x 6 float4 nontemporal stores.
//
// XCD swizzle: dispatch index d -> XCD d%8 (round-robin). We map d so that
// all 32 units of an element e land on the XCD e%8 -> the element's 16 KB
// disp row is fetched into exactly one XCD's L2 (kills the 8x read
// amplification seen without swizzling).

#define N_TIME 4096

typedef float f32x4 __attribute__((ext_vector_type(4)));  // native vector:
// __builtin_nontemporal_store rejects HIP's float4 struct, accepts this.

__global__ __launch_bounds__(256) void state_hist_kernel(
    const float* __restrict__ disp,   // [2048][4096]
    const float* __restrict__ param,  // [1]
    float* __restrict__ out)          // [2048][8][4096][6]
{
    __shared__ float s_disp[1025];

    const int d = blockIdx.x;
    const int j = threadIdx.x;

    // --- XCD-aware de-swizzle: d -> (e, g, chunk) with e % 8 == d % 8 ---
    const int xcd     = d & 7;
    const int k       = d >> 3;        // 0..8191
    const int e_local = k >> 5;        // 0..255
    const int unit    = k & 31;        // 0..31  (g*4 + chunk)
    const int e       = (e_local << 3) | xcd;
    const int g       = unit >> 2;
    const int tbase   = (unit & 3) * 1024;
    const int b_lin   = (e << 5) | unit;   // linear output block index

    // Stage this block's 1024 disp values into LDS (float4 coalesced loads).
    const f32x4* disp4 = reinterpret_cast<const f32x4*>(disp + e * N_TIME + tbase);
    reinterpret_cast<f32x4*>(s_disp)[j] = disp4[j];
    if (j == 0) s_disp[1024] = 0.0f;   // pad for unconditional t+1 read
    __syncthreads();

    const float p = param[0];
    const float factor = (p + p * p) * (float)(g + 1);

    f32x4* out4 = reinterpret_cast<f32x4*>(out) + (size_t)b_lin * 1536;

    #pragma unroll
    for (int kk = 0; kk < 6; ++kk) {
        const int i4 = kk * 256 + j;      // float4 index within block region
        const int r  = i4 * 4;            // float index within block region
        const int t  = r / 6;             // const divisor -> mul+shift
        const int c  = r - t * 6;         // in {0, 2, 4}
        const float v0 = factor * s_disp[t];
        const float v1 = factor * s_disp[t + 1];
        f32x4 o;
        o.x = v0;
        o.y = v0;
        o.z = (c == 4) ? v1 : v0;         // c==4: last two floats belong to t+1
        o.w = (c == 4) ? v1 : v0;
        __builtin_nontemporal_store(o, &out4[i4]);
    }
}

extern "C" void kernel_launch(void* const* d_in, const int* in_sizes, int n_in,
                              void* d_out, int out_size, void* d_ws, size_t ws_size,
                              hipStream_t stream) {
    const float* disp  = (const float*)d_in[0];   // elements_disp_hist [2048*4096]
    // d_in[1] = time_hist (unused)
    const float* param = (const float*)d_in[2];   // param_1 [1]
    float* out = (float*)d_out;                   // 2048*8*4096*6 floats

    const int n_elem = in_sizes[0] / N_TIME;      // 2048
    const int grid   = n_elem * 8 * 4;            // 65536 blocks

    state_hist_kernel<<<grid, 256, 0, stream>>>(disp, param, out);
}